// Round 11
// baseline (921.770 us; speedup 1.0000x reference)
//
#include <hip/hip_runtime.h>
#include <hip/hip_bf16.h>
#include <cstdint>
#include <cstddef>

#define CH    64
#define IMG   512
#define PLANE (IMG * IMG)   // 262144
#define NSPX  256

// ---------------------------------------------------------------------------
// Pooling v2: one wave per (b, sp). Per row: 8 dense float4 wave-loads stage
// the row (64ch x 32px) into the LDS transpose buffer; lane = channel then
// accumulates the row's 32 pixels in index order. Per-channel op order is
// row-major sequential == round-3 pool (bit-exact), loads are dense.
// Next-row register prefetch overlaps HBM latency with the add chain.
// ---------------------------------------------------------------------------
__global__ __launch_bounds__(64) void ssn_pool2(const float* __restrict__ f,
                                                float* __restrict__ numer,
                                                float* __restrict__ denom) {
  const int wg = blockIdx.x;            // b*256 + sp
  const int b = wg >> 8, sp = wg & 255;
  const int sr = sp >> 4, sc = sp & 15;
  const int lane = threadIdx.x;         // 0..63
  const int y0 = sr * 32, x0 = sc * 32;
  const int cbase = lane >> 3;          // 0..7
  const int xq    = (lane & 7) * 4;     // 0,4,...,28

  __shared__ __align__(16) float vb[32][65];

  const float* fB = f + (size_t)b * CH * PLANE;

  float4 cur[8], nxt[8];
  #pragma unroll
  for (int j = 0; j < 8; ++j) {
    const int c = j * 8 + cbase;
    cur[j] = *(const float4*)(fB + (size_t)c * PLANE + (size_t)y0 * IMG + x0 + xq);
  }

  float acc = 0.f;
  for (int y = 0; y < 32; ++y) {
    if (y < 31) {
      #pragma unroll
      for (int j = 0; j < 8; ++j) {
        const int c = j * 8 + cbase;
        nxt[j] = *(const float4*)(fB + (size_t)c * PLANE +
                                  (size_t)(y0 + y + 1) * IMG + x0 + xq);
      }
    }
    #pragma unroll
    for (int j = 0; j < 8; ++j) {
      const int c = j * 8 + cbase;
      vb[xq + 0][c] = cur[j].x;
      vb[xq + 1][c] = cur[j].y;
      vb[xq + 2][c] = cur[j].z;
      vb[xq + 3][c] = cur[j].w;
    }
    __builtin_amdgcn_wave_barrier();
    // lane = channel: row pixels 0..31 in index order (bit-exact chain)
    #pragma unroll 8
    for (int x = 0; x < 32; ++x) acc = __fadd_rn(acc, vb[x][lane]);
    __builtin_amdgcn_wave_barrier();
    if (y < 31) {
      #pragma unroll
      for (int j = 0; j < 8; ++j) cur[j] = nxt[j];
    }
  }
  numer[((size_t)wg << 6) + lane] = acc;
  if (lane == 0) denom[wg] = 1024.0f;
}

// ---------------------------------------------------------------------------
// One SSN iteration. Arithmetic bit-identical to rounds 3/5/7; staging now
// software-pipelined: row r+1's 8 float4 loads are issued before computing
// row r, hiding HBM latency under the ~900-op compute phase (T14 split).
// ---------------------------------------------------------------------------
__global__ __launch_bounds__(256, 3) void ssn_iter2(const float* __restrict__ f,
    const float* __restrict__ numer_in, const float* __restrict__ denom_in,
    float* __restrict__ Pnum, float* __restrict__ Pden,
    float* __restrict__ labels_out, const int final_flag) {
  const int wg = blockIdx.x;
  const int b = wg >> 8, sp = wg & 255;
  const int sr = sp >> 4, sc = sp & 15;
  const int tid = threadIdx.x;
  const int wave = tid >> 6, lane = tid & 63;
  const int p = lane & 31, h = lane >> 5;   // pixel-in-row, channel-half

  __shared__ float cent[9][64];
  __shared__ float nw[4][9][64];
  __shared__ float dw[4][9];
  __shared__ int   nbr_s[9];
  __shared__ __align__(16) float v_lds[4][32][65];  // [wave][px][ch], pad 65
  __shared__ __align__(16) float w_lds[4][32][12];  // 9 weights + pad

  if (tid < 9) {
    int dr = tid / 3 - 1, dc = tid % 3 - 1;
    int nr = sr + dr, nc = sc + dc;
    bool valid = (nr >= 0) && (nr < 16) && (nc >= 0) && (nc < 16);
    nbr_s[tid] = valid ? (nr * 16 + nc) : -1;
  }
  __syncthreads();
  // centroids = numer/(denom + 1e-16): same arithmetic as reference's spix
  for (int i = tid; i < 9 * 64; i += 256) {
    int k = i >> 6, c = i & 63;
    int ns = nbr_s[k];
    float v = 0.f;
    if (ns >= 0) {
      int base = (b << 8) + ns;
      v = numer_in[((size_t)base << 6) + c] / (denom_in[base] + 1e-16f);
    }
    cent[k][c] = v;
  }
  __syncthreads();

  int nbk[9];
  #pragma unroll
  for (int k = 0; k < 9; ++k) nbk[k] = nbr_s[k];

  float nacc[9], wsA[9];
  #pragma unroll
  for (int k = 0; k < 9; ++k) { nacc[k] = 0.f; wsA[k] = 0.f; }

  const int y0 = sr * 32, x0 = sc * 32;
  float (* __restrict__ vb)[65] = v_lds[wave];
  float (* __restrict__ wb)[12] = w_lds[wave];

  // staging decomposition: lane -> (channel-octet, x-quad)
  const int cbase = lane >> 3;          // 0..7
  const int xq    = (lane & 7) * 4;     // 0,4,...,28
  const float* fRow = f + (size_t)b * CH * PLANE + (size_t)x0 + xq;

  float4 cur[8], nxt[8];
  {
    const int gy = y0 + wave * 8;
    #pragma unroll
    for (int j = 0; j < 8; ++j) {
      const int c = j * 8 + cbase;
      cur[j] = *(const float4*)(fRow + (size_t)c * PLANE + (size_t)gy * IMG);
    }
  }

  for (int r = 0; r < 8; ++r) {
    const int gy = y0 + wave * 8 + r;

    // ---- prefetch next row (issued early; completes under compute) ----
    if (r < 7) {
      #pragma unroll
      for (int j = 0; j < 8; ++j) {
        const int c = j * 8 + cbase;
        nxt[j] = *(const float4*)(fRow + (size_t)c * PLANE + (size_t)(gy + 1) * IMG);
      }
    }

    // ---- stage current row into the per-wave LDS transpose buffer ----
    #pragma unroll
    for (int j = 0; j < 8; ++j) {
      const int c = j * 8 + cbase;
      vb[xq + 0][c] = cur[j].x;
      vb[xq + 1][c] = cur[j].y;
      vb[xq + 2][c] = cur[j].z;
      vb[xq + 3][c] = cur[j].w;
    }
    __builtin_amdgcn_wave_barrier();

    // ---- phase 1: lane ~ (pixel p, channel-half h); bit-exact chain ----
    float dpart[9];
    #pragma unroll
    for (int k = 0; k < 9; ++k) dpart[k] = 0.f;
    #pragma unroll
    for (int cit = 0; cit < 32; ++cit) {
      float v = vb[p][32 * h + cit];
      #pragma unroll
      for (int k = 0; k < 9; ++k) {
        float d = v - cent[k][32 * h + cit];
        dpart[k] = fmaf(d, d, dpart[k]);
      }
    }
    float dist[9];
    #pragma unroll
    for (int k = 0; k < 9; ++k) {
      float o = __shfl_xor(dpart[k], 32);
      dist[k] = (nbk[k] >= 0) ? (dpart[k] + o) : __builtin_inff();
    }
    // softmax(-dist): exponent = m - dist, m = min(dist)
    float m = dist[0];
    #pragma unroll
    for (int k = 1; k < 9; ++k) m = fminf(m, dist[k]);
    float w[9], s = 0.f;
    #pragma unroll
    for (int k = 0; k < 9; ++k) { w[k] = expf(m - dist[k]); s = __fadd_rn(s, w[k]); }
    #pragma unroll
    for (int k = 0; k < 9; ++k) w[k] = w[k] / s;

    if (final_flag) {
      // argmax of normalized affinity, first occurrence on ties
      float ba = w[0]; int bs = nbk[0];
      #pragma unroll
      for (int k = 1; k < 9; ++k)
        if (w[k] > ba) { ba = w[k]; bs = nbk[k]; }
      if (h == 0)
        labels_out[(size_t)b * PLANE + (size_t)gy * IMG + x0 + p] = (float)bs;
    }

    if (h == 0) {
      *(float4*)&wb[p][0] = make_float4(w[0], w[1], w[2], w[3]);
      *(float4*)&wb[p][4] = make_float4(w[4], w[5], w[6], w[7]);
      wb[p][8] = w[8];
    }

    // ---- phase 2: lane = channel c; mul-then-add (no fma), same order ----
    #pragma unroll 8
    for (int pp = 0; pp < 32; ++pp) {
      float v  = vb[pp][lane];
      float4 wA = *(const float4*)&wb[pp][0];
      float4 wB = *(const float4*)&wb[pp][4];
      float  w8 = wb[pp][8];
      nacc[0] = __fadd_rn(nacc[0], __fmul_rn(wA.x, v));
      nacc[1] = __fadd_rn(nacc[1], __fmul_rn(wA.y, v));
      nacc[2] = __fadd_rn(nacc[2], __fmul_rn(wA.z, v));
      nacc[3] = __fadd_rn(nacc[3], __fmul_rn(wA.w, v));
      nacc[4] = __fadd_rn(nacc[4], __fmul_rn(wB.x, v));
      nacc[5] = __fadd_rn(nacc[5], __fmul_rn(wB.y, v));
      nacc[6] = __fadd_rn(nacc[6], __fmul_rn(wB.z, v));
      nacc[7] = __fadd_rn(nacc[7], __fmul_rn(wB.w, v));
      nacc[8] = __fadd_rn(nacc[8], __fmul_rn(w8,  v));
      wsA[0] = __fadd_rn(wsA[0], wA.x);
      wsA[1] = __fadd_rn(wsA[1], wA.y);
      wsA[2] = __fadd_rn(wsA[2], wA.z);
      wsA[3] = __fadd_rn(wsA[3], wA.w);
      wsA[4] = __fadd_rn(wsA[4], wB.x);
      wsA[5] = __fadd_rn(wsA[5], wB.y);
      wsA[6] = __fadd_rn(wsA[6], wB.z);
      wsA[7] = __fadd_rn(wsA[7], wB.w);
      wsA[8] = __fadd_rn(wsA[8], w8);
    }
    __builtin_amdgcn_wave_barrier();   // don't let next staging overlap reads

    if (r < 7) {
      #pragma unroll
      for (int j = 0; j < 8; ++j) cur[j] = nxt[j];
    }
  }

  // per-wave partials -> LDS (no atomics)
  #pragma unroll
  for (int k = 0; k < 9; ++k) nw[wave][k][lane] = nacc[k];
  if (lane == 0) {
    #pragma unroll
    for (int k = 0; k < 9; ++k) dw[wave][k] = wsA[k];
  }
  __syncthreads();

  // fixed-order combine: wave0 + wave1 + wave2 + wave3
  for (int i = tid; i < 9 * 64; i += 256) {
    int k = i >> 6, c = i & 63;
    float s01  = __fadd_rn(nw[0][k][c], nw[1][k][c]);
    float s012 = __fadd_rn(s01, nw[2][k][c]);
    Pnum[((size_t)wg * 9 + k) * 64 + c] = __fadd_rn(s012, nw[3][k][c]);
  }
  if (tid < 9) {
    float s01  = __fadd_rn(dw[0][tid], dw[1][tid]);
    float s012 = __fadd_rn(s01, dw[2][tid]);
    Pden[wg * 9 + tid] = __fadd_rn(s012, dw[3][tid]);
  }
}

// ---------------------------------------------------------------------------
// Deterministic gather (round-3 verbatim): k ASCENDING matches the reference's
// numer += seg_sum_k order. final_mode: write spix = numer/(denom+1e-16).
// ---------------------------------------------------------------------------
__global__ __launch_bounds__(64) void ssn_gather(const float* __restrict__ Pnum,
    const float* __restrict__ Pden, float* __restrict__ numer_out,
    float* __restrict__ denom_out, float* __restrict__ spix_out,
    const int final_mode) {
  const int wg = blockIdx.x;           // b*256 + sp
  const int b = wg >> 8, sp = wg & 255;
  const int sr = sp >> 4, sc = sp & 15;
  const int c = threadIdx.x;           // 0..63
  float acc = 0.f, den = 0.f;
  #pragma unroll
  for (int k = 0; k < 9; ++k) {
    int dr = k / 3 - 1, dc = k % 3 - 1;
    int ssr = sr - dr, ssc = sc - dc;
    if (ssr >= 0 && ssr < 16 && ssc >= 0 && ssc < 16) {
      int src = (b << 8) + ssr * 16 + ssc;
      acc = __fadd_rn(acc, Pnum[((size_t)src * 9 + k) * 64 + c]);
      den = __fadd_rn(den, Pden[src * 9 + k]);
    }
  }
  if (final_mode) {
    spix_out[((size_t)wg << 6) + c] = acc / (den + 1e-16f);
  } else {
    numer_out[((size_t)wg << 6) + c] = acc;
    if (c == 0) denom_out[wg] = den;
  }
}

// ===========================================================================
extern "C" void kernel_launch(void* const* d_in, const int* in_sizes, int n_in,
                              void* d_out, int out_size, void* d_ws, size_t ws_size,
                              hipStream_t stream) {
  const float* f = (const float*)d_in[0];
  float* out = (float*)d_out;
  float* ws  = (float*)d_ws;
  float* labels = out + 4 * NSPX * CH;

  float* Pnum   = ws;                  // 1024*9*64 = 589824 f32
  float* Pden   = ws + 589824;         // 1024*9    =   9216 f32
  float* numerA = ws + 599040;         // 65536 f32
  float* numerB = ws + 664576;         // 65536 f32
  float* denomA = ws + 730112;         // 1024 f32
  float* denomB = ws + 731136;         // 1024 f32

  ssn_pool2<<<dim3(1024), dim3(64), 0, stream>>>(f, numerA, denomA);

  float* ni = numerA; float* di = denomA;
  float* no = numerB; float* dn = denomB;
  for (int it = 0; it < 5; ++it) {
    ssn_iter2<<<dim3(1024), dim3(256), 0, stream>>>(f, ni, di, Pnum, Pden, labels,
                                                    (it == 4) ? 1 : 0);
    if (it < 4) {
      ssn_gather<<<dim3(1024), dim3(64), 0, stream>>>(Pnum, Pden, no, dn, nullptr, 0);
      float* t;
      t = ni; ni = no; no = t;
      t = di; di = dn; dn = t;
    } else {
      ssn_gather<<<dim3(1024), dim3(64), 0, stream>>>(Pnum, Pden, nullptr, nullptr, out, 1);
    }
  }
}

// Round 13
// 799.280 us; speedup vs baseline: 1.1532x; 1.1532x over previous
//
#include <hip/hip_runtime.h>
#include <hip/hip_bf16.h>
#include <cstdint>
#include <cstddef>

#define CH    64
#define IMG   512
#define PLANE (IMG * IMG)   // 262144
#define NSPX  256

// ---------------------------------------------------------------------------
// Pooling v2 (round-11 proven, bit-exact vs round-3 pool): one wave per
// (b, sp). Per row: 8 dense float4 wave-loads stage the row (64ch x 32px)
// into the LDS transpose buffer; lane = channel accumulates the row's 32
// pixels in index order -> per-channel op order is row-major sequential.
// ---------------------------------------------------------------------------
__global__ __launch_bounds__(64) void ssn_pool2(const float* __restrict__ f,
                                                float* __restrict__ numer,
                                                float* __restrict__ denom) {
  const int wg = blockIdx.x;            // b*256 + sp
  const int b = wg >> 8, sp = wg & 255;
  const int sr = sp >> 4, sc = sp & 15;
  const int lane = threadIdx.x;         // 0..63
  const int y0 = sr * 32, x0 = sc * 32;
  const int cbase = lane >> 3;          // 0..7
  const int xq    = (lane & 7) * 4;     // 0,4,...,28

  __shared__ __align__(16) float vb[32][65];

  const float* fB = f + (size_t)b * CH * PLANE;

  float4 cur[8], nxt[8];
  #pragma unroll
  for (int j = 0; j < 8; ++j) {
    const int c = j * 8 + cbase;
    cur[j] = *(const float4*)(fB + (size_t)c * PLANE + (size_t)y0 * IMG + x0 + xq);
  }

  float acc = 0.f;
  for (int y = 0; y < 32; ++y) {
    if (y < 31) {
      #pragma unroll
      for (int j = 0; j < 8; ++j) {
        const int c = j * 8 + cbase;
        nxt[j] = *(const float4*)(fB + (size_t)c * PLANE +
                                  (size_t)(y0 + y + 1) * IMG + x0 + xq);
      }
    }
    #pragma unroll
    for (int j = 0; j < 8; ++j) {
      const int c = j * 8 + cbase;
      vb[xq + 0][c] = cur[j].x;
      vb[xq + 1][c] = cur[j].y;
      vb[xq + 2][c] = cur[j].z;
      vb[xq + 3][c] = cur[j].w;
    }
    __builtin_amdgcn_wave_barrier();
    // lane = channel: row pixels 0..31 in index order (bit-exact chain)
    #pragma unroll 8
    for (int x = 0; x < 32; ++x) acc = __fadd_rn(acc, vb[x][lane]);
    __builtin_amdgcn_wave_barrier();
    if (y < 31) {
      #pragma unroll
      for (int j = 0; j < 8; ++j) cur[j] = nxt[j];
    }
  }
  numer[((size_t)wg << 6) + lane] = acc;
  if (lane == 0) denom[wg] = 1024.0f;
}

// ---------------------------------------------------------------------------
// One SSN iteration — EXACT round-7 form (no register prefetch; 84 VGPR).
// Per row: 8 float4 wave-loads stage 64ch x 32px into the per-wave LDS
// transpose buffer; distance chain reads LDS in the original cit order.
// Arithmetic bit-identical to rounds 3/5/7/11.
// ---------------------------------------------------------------------------
__global__ __launch_bounds__(256, 3) void ssn_iter2(const float* __restrict__ f,
    const float* __restrict__ numer_in, const float* __restrict__ denom_in,
    float* __restrict__ Pnum, float* __restrict__ Pden,
    float* __restrict__ labels_out, const int final_flag) {
  const int wg = blockIdx.x;
  const int b = wg >> 8, sp = wg & 255;
  const int sr = sp >> 4, sc = sp & 15;
  const int tid = threadIdx.x;
  const int wave = tid >> 6, lane = tid & 63;
  const int p = lane & 31, h = lane >> 5;   // pixel-in-row, channel-half

  __shared__ float cent[9][64];
  __shared__ float nw[4][9][64];
  __shared__ float dw[4][9];
  __shared__ int   nbr_s[9];
  __shared__ __align__(16) float v_lds[4][32][65];  // [wave][px][ch], pad 65
  __shared__ __align__(16) float w_lds[4][32][12];  // 9 weights + pad

  if (tid < 9) {
    int dr = tid / 3 - 1, dc = tid % 3 - 1;
    int nr = sr + dr, nc = sc + dc;
    bool valid = (nr >= 0) && (nr < 16) && (nc >= 0) && (nc < 16);
    nbr_s[tid] = valid ? (nr * 16 + nc) : -1;
  }
  __syncthreads();
  // centroids = numer/(denom + 1e-16): same arithmetic as reference's spix
  for (int i = tid; i < 9 * 64; i += 256) {
    int k = i >> 6, c = i & 63;
    int ns = nbr_s[k];
    float v = 0.f;
    if (ns >= 0) {
      int base = (b << 8) + ns;
      v = numer_in[((size_t)base << 6) + c] / (denom_in[base] + 1e-16f);
    }
    cent[k][c] = v;
  }
  __syncthreads();

  int nbk[9];
  #pragma unroll
  for (int k = 0; k < 9; ++k) nbk[k] = nbr_s[k];

  float nacc[9], wsA[9];
  #pragma unroll
  for (int k = 0; k < 9; ++k) { nacc[k] = 0.f; wsA[k] = 0.f; }

  const int y0 = sr * 32, x0 = sc * 32;
  float (* __restrict__ vb)[65] = v_lds[wave];
  float (* __restrict__ wb)[12] = w_lds[wave];

  // staging decomposition: lane -> (channel-octet, x-quad)
  const int cbase = lane >> 3;          // 0..7
  const int xq    = (lane & 7) * 4;     // 0,4,...,28

  for (int r = 0; r < 8; ++r) {
    const int gy = y0 + wave * 8 + r;

    // ---- staging: 8 x float4 wave-loads, dense per instruction ----
    #pragma unroll
    for (int j = 0; j < 8; ++j) {
      const int c = j * 8 + cbase;
      const float4 v4 = *(const float4*)(
          f + (size_t)(b * CH + c) * PLANE + (size_t)gy * IMG + x0 + xq);
      vb[xq + 0][c] = v4.x;
      vb[xq + 1][c] = v4.y;
      vb[xq + 2][c] = v4.z;
      vb[xq + 3][c] = v4.w;
    }
    __builtin_amdgcn_wave_barrier();   // order staging before reads (no HW cost)

    // ---- phase 1: lane ~ (pixel p, channel-half h); bit-exact chain ----
    float dpart[9];
    #pragma unroll
    for (int k = 0; k < 9; ++k) dpart[k] = 0.f;
    #pragma unroll
    for (int cit = 0; cit < 32; ++cit) {
      float v = vb[p][32 * h + cit];
      #pragma unroll
      for (int k = 0; k < 9; ++k) {
        float d = v - cent[k][32 * h + cit];
        dpart[k] = fmaf(d, d, dpart[k]);
      }
    }
    float dist[9];
    #pragma unroll
    for (int k = 0; k < 9; ++k) {
      float o = __shfl_xor(dpart[k], 32);
      dist[k] = (nbk[k] >= 0) ? (dpart[k] + o) : __builtin_inff();
    }
    // softmax(-dist): exponent = m - dist, m = min(dist)
    float m = dist[0];
    #pragma unroll
    for (int k = 1; k < 9; ++k) m = fminf(m, dist[k]);
    float w[9], s = 0.f;
    #pragma unroll
    for (int k = 0; k < 9; ++k) { w[k] = expf(m - dist[k]); s = __fadd_rn(s, w[k]); }
    #pragma unroll
    for (int k = 0; k < 9; ++k) w[k] = w[k] / s;

    if (final_flag) {
      // argmax of normalized affinity, first occurrence on ties
      float ba = w[0]; int bs = nbk[0];
      #pragma unroll
      for (int k = 1; k < 9; ++k)
        if (w[k] > ba) { ba = w[k]; bs = nbk[k]; }
      if (h == 0)
        labels_out[(size_t)b * PLANE + (size_t)gy * IMG + x0 + p] = (float)bs;
    }

    if (h == 0) {
      *(float4*)&wb[p][0] = make_float4(w[0], w[1], w[2], w[3]);
      *(float4*)&wb[p][4] = make_float4(w[4], w[5], w[6], w[7]);
      wb[p][8] = w[8];
    }

    // ---- phase 2: lane = channel c; mul-then-add (no fma), same order ----
    #pragma unroll 8
    for (int pp = 0; pp < 32; ++pp) {
      float v  = vb[pp][lane];
      float4 wA = *(const float4*)&wb[pp][0];
      float4 wB = *(const float4*)&wb[pp][4];
      float  w8 = wb[pp][8];
      nacc[0] = __fadd_rn(nacc[0], __fmul_rn(wA.x, v));
      nacc[1] = __fadd_rn(nacc[1], __fmul_rn(wA.y, v));
      nacc[2] = __fadd_rn(nacc[2], __fmul_rn(wA.z, v));
      nacc[3] = __fadd_rn(nacc[3], __fmul_rn(wA.w, v));
      nacc[4] = __fadd_rn(nacc[4], __fmul_rn(wB.x, v));
      nacc[5] = __fadd_rn(nacc[5], __fmul_rn(wB.y, v));
      nacc[6] = __fadd_rn(nacc[6], __fmul_rn(wB.z, v));
      nacc[7] = __fadd_rn(nacc[7], __fmul_rn(wB.w, v));
      nacc[8] = __fadd_rn(nacc[8], __fmul_rn(w8,  v));
      wsA[0] = __fadd_rn(wsA[0], wA.x);
      wsA[1] = __fadd_rn(wsA[1], wA.y);
      wsA[2] = __fadd_rn(wsA[2], wA.z);
      wsA[3] = __fadd_rn(wsA[3], wA.w);
      wsA[4] = __fadd_rn(wsA[4], wB.x);
      wsA[5] = __fadd_rn(wsA[5], wB.y);
      wsA[6] = __fadd_rn(wsA[6], wB.z);
      wsA[7] = __fadd_rn(wsA[7], wB.w);
      wsA[8] = __fadd_rn(wsA[8], w8);
    }
    __builtin_amdgcn_wave_barrier();   // don't let next staging overlap reads
  }

  // per-wave partials -> LDS (no atomics)
  #pragma unroll
  for (int k = 0; k < 9; ++k) nw[wave][k][lane] = nacc[k];
  if (lane == 0) {
    #pragma unroll
    for (int k = 0; k < 9; ++k) dw[wave][k] = wsA[k];
  }
  __syncthreads();

  // fixed-order combine: wave0 + wave1 + wave2 + wave3
  for (int i = tid; i < 9 * 64; i += 256) {
    int k = i >> 6, c = i & 63;
    float s01  = __fadd_rn(nw[0][k][c], nw[1][k][c]);
    float s012 = __fadd_rn(s01, nw[2][k][c]);
    Pnum[((size_t)wg * 9 + k) * 64 + c] = __fadd_rn(s012, nw[3][k][c]);
  }
  if (tid < 9) {
    float s01  = __fadd_rn(dw[0][tid], dw[1][tid]);
    float s012 = __fadd_rn(s01, dw[2][tid]);
    Pden[wg * 9 + tid] = __fadd_rn(s012, dw[3][tid]);
  }
}

// ---------------------------------------------------------------------------
// Deterministic gather (round-3 verbatim): k ASCENDING matches the reference's
// numer += seg_sum_k order. final_mode: write spix = numer/(denom+1e-16).
// ---------------------------------------------------------------------------
__global__ __launch_bounds__(64) void ssn_gather(const float* __restrict__ Pnum,
    const float* __restrict__ Pden, float* __restrict__ numer_out,
    float* __restrict__ denom_out, float* __restrict__ spix_out,
    const int final_mode) {
  const int wg = blockIdx.x;           // b*256 + sp
  const int b = wg >> 8, sp = wg & 255;
  const int sr = sp >> 4, sc = sp & 15;
  const int c = threadIdx.x;           // 0..63
  float acc = 0.f, den = 0.f;
  #pragma unroll
  for (int k = 0; k < 9; ++k) {
    int dr = k / 3 - 1, dc = k % 3 - 1;
    int ssr = sr - dr, ssc = sc - dc;
    if (ssr >= 0 && ssr < 16 && ssc >= 0 && ssc < 16) {
      int src = (b << 8) + ssr * 16 + ssc;
      acc = __fadd_rn(acc, Pnum[((size_t)src * 9 + k) * 64 + c]);
      den = __fadd_rn(den, Pden[src * 9 + k]);
    }
  }
  if (final_mode) {
    spix_out[((size_t)wg << 6) + c] = acc / (den + 1e-16f);
  } else {
    numer_out[((size_t)wg << 6) + c] = acc;
    if (c == 0) denom_out[wg] = den;
  }
}

// ===========================================================================
extern "C" void kernel_launch(void* const* d_in, const int* in_sizes, int n_in,
                              void* d_out, int out_size, void* d_ws, size_t ws_size,
                              hipStream_t stream) {
  const float* f = (const float*)d_in[0];
  float* out = (float*)d_out;
  float* ws  = (float*)d_ws;
  float* labels = out + 4 * NSPX * CH;

  float* Pnum   = ws;                  // 1024*9*64 = 589824 f32
  float* Pden   = ws + 589824;         // 1024*9    =   9216 f32
  float* numerA = ws + 599040;         // 65536 f32
  float* numerB = ws + 664576;         // 65536 f32
  float* denomA = ws + 730112;         // 1024 f32
  float* denomB = ws + 731136;         // 1024 f32

  ssn_pool2<<<dim3(1024), dim3(64), 0, stream>>>(f, numerA, denomA);

  float* ni = numerA; float* di = denomA;
  float* no = numerB; float* dn = denomB;
  for (int it = 0; it < 5; ++it) {
    ssn_iter2<<<dim3(1024), dim3(256), 0, stream>>>(f, ni, di, Pnum, Pden, labels,
                                                    (it == 4) ? 1 : 0);
    if (it < 4) {
      ssn_gather<<<dim3(1024), dim3(64), 0, stream>>>(Pnum, Pden, no, dn, nullptr, 0);
      float* t;
      t = ni; ni = no; no = t;
      t = di; di = dn; dn = t;
    } else {
      ssn_gather<<<dim3(1024), dim3(64), 0, stream>>>(Pnum, Pden, nullptr, nullptr, out, 1);
    }
  }
}